// Round 6
// baseline (1289.537 us; speedup 1.0000x reference)
//
#include <hip/hip_runtime.h>
#include <stdint.h>

typedef unsigned short ushort_t;
typedef __attribute__((ext_vector_type(8))) short bf8_t;     // 8 x bf16 (4 VGPRs)
typedef __attribute__((ext_vector_type(4))) float f4_t;      // MFMA accumulator
typedef __attribute__((ext_vector_type(4))) unsigned short us4_t;

#define TT 128

__device__ __forceinline__ ushort_t f2bf(float f) {
  uint32_t u = __builtin_bit_cast(uint32_t, f);
  u += 0x7fffu + ((u >> 16) & 1u);
  return (ushort_t)(u >> 16);
}
__device__ __forceinline__ float bf2f(ushort_t h) {
  uint32_t u = ((uint32_t)h) << 16;
  return __builtin_bit_cast(float, u);
}
__device__ __forceinline__ float sigm(float x) {
  return __builtin_amdgcn_rcpf(1.f + __expf(-x));
}
__device__ __forceinline__ float tanh_f(float x) {
  return 1.f - 2.f * __builtin_amdgcn_rcpf(1.f + __expf(2.f * x));
}

// ---- LLC-coherent (sc0 sc1) exchange primitives (placement-agnostic) ----
__device__ __forceinline__ void x_store16(void* p, bf8_t v) {
  asm volatile("global_store_dwordx4 %0, %1, off sc0 sc1" :: "v"(p), "v"(v) : "memory");
}
__device__ __forceinline__ void x_store_flag(unsigned* p, unsigned v) {
  asm volatile("global_store_dword %0, %1, off sc0 sc1" :: "v"(p), "v"(v) : "memory");
}
// issue 4 frag loads (no wait; consumer fences with counted vmcnt + sched_barrier)
__device__ __forceinline__ void x_load4_issue(const void* p, bf8_t f[4]) {
  asm volatile(
      "global_load_dwordx4 %0, %4, off sc0 sc1\n\t"
      "global_load_dwordx4 %1, %4, off offset:1024 sc0 sc1\n\t"
      "global_load_dwordx4 %2, %4, off offset:2048 sc0 sc1\n\t"
      "global_load_dwordx4 %3, %4, off offset:3072 sc0 sc1"
      : "=&v"(f[0]), "=&v"(f[1]), "=&v"(f[2]), "=&v"(f[3]) : "v"(p) : "memory");
}

// ---------- pack kernels ----------
// Gate-interleaved: physical output col n = col*4 + gate.  WT[n][k] = W_{g=n&3}[k][j=n>>2]
__global__ void k_pack_w(const float* W0, const float* W1, const float* W2, const float* W3,
                         ushort_t* __restrict__ o) {
  int idx = blockIdx.x * 256 + threadIdx.x;   // 0..262143
  int n = idx >> 8, k = idx & 255;
  int g = n & 3, j = n >> 2;
  const float* Wg = g == 0 ? W0 : g == 1 ? W1 : g == 2 ? W2 : W3;
  o[(size_t)n * 256 + k] = f2bf(Wg[k * 256 + j]);
}

// U frag pack: UPJ[((q*8+w)*8 + ktS)*4 + g][lane][e]; ktS local (own k-half first):
// global kt = (ktS + 4*q) & 7; col = q*128 + w*16 + (lane&15); k = ktG*32+(lane>>4)*8+e
__global__ void k_pack_u(const float* U0, const float* U1, const float* U2, const float* U3,
                         ushort_t* __restrict__ o) {
  int idx = blockIdx.x * 256 + threadIdx.x;   // 0..32767
  int lane = idx & 63, g = (idx >> 6) & 3, ktS = (idx >> 8) & 7,
      w = (idx >> 11) & 7, q = (idx >> 14) & 1;
  const float* Ug = g == 0 ? U0 : g == 1 ? U1 : g == 2 ? U2 : U3;
  int ktG = (ktS + 4 * q) & 7;
  int col = q * 128 + w * 16 + (lane & 15);
  int kb = ktG * 32 + (lane >> 4) * 8;
#pragma unroll
  for (int e = 0; e < 8; ++e)
    o[(size_t)idx * 8 + e] = f2bf(Ug[(size_t)(kb + e) * 256 + col]);
}

// bias2[n] (n = j*4+g) = bW_g[j] + bU_g[j]
__global__ void k_bias(const float* a0, const float* a1, const float* a2, const float* a3,
                       const float* b0, const float* b1, const float* b2, const float* b3,
                       float* __restrict__ o) {
  int n = blockIdx.x * 256 + threadIdx.x;  // 0..1023
  int g = n & 3, j = n >> 2;
  const float* pa = g == 0 ? a0 : g == 1 ? a1 : g == 2 ? a2 : a3;
  const float* pb = g == 0 ? b0 : g == 1 ? b1 : g == 2 ? b2 : b3;
  o[n] = pa[j] + pb[j];
}

// ---------- K1: P = emb @ W_all (emb f32 read + convert fused; bf16 MFMA) ----------
__global__ __launch_bounds__(256) void k1_gemm(const float* __restrict__ A,      // emb f32 [32000][256]
                                               const ushort_t* __restrict__ Bm,  // WT bf16 [1024][256]
                                               ushort_t* __restrict__ P) {       // [32000][1024]
  __shared__ ushort_t Al[128 * 32];
  __shared__ ushort_t Bl[128 * 32];
  const int tid = threadIdx.x;
  const int lane = tid & 63;
  const int w = tid >> 6;
  const int mt = blockIdx.x >> 3;
  const int nt = blockIdx.x & 7;
  const int m0 = mt * 128, n0 = nt * 128;
  const int qr = (w >> 1) * 64, qc = (w & 1) * 64;

  f4_t acc[4][4];
#pragma unroll
  for (int i = 0; i < 4; ++i)
#pragma unroll
    for (int j = 0; j < 4; ++j) acc[i][j] = f4_t{0.f, 0.f, 0.f, 0.f};

  const int r0 = tid >> 2, s0 = tid & 3;  // rows 0..63
  const int r1 = 64 + r0;                 // rows 64..127

  for (int k0 = 0; k0 < 256; k0 += 32) {
    float4 a00 = *(const float4*)(A + (size_t)(m0 + r0) * 256 + k0 + s0 * 8);
    float4 a01 = *(const float4*)(A + (size_t)(m0 + r0) * 256 + k0 + s0 * 8 + 4);
    float4 a10 = *(const float4*)(A + (size_t)(m0 + r1) * 256 + k0 + s0 * 8);
    float4 a11 = *(const float4*)(A + (size_t)(m0 + r1) * 256 + k0 + s0 * 8 + 4);
    bf8_t b0 = *(const bf8_t*)(Bm + (size_t)(n0 + r0) * 256 + k0 + s0 * 8);
    bf8_t b1 = *(const bf8_t*)(Bm + (size_t)(n0 + r1) * 256 + k0 + s0 * 8);
    bf8_t pa0, pa1;
    pa0[0] = (short)f2bf(a00.x); pa0[1] = (short)f2bf(a00.y);
    pa0[2] = (short)f2bf(a00.z); pa0[3] = (short)f2bf(a00.w);
    pa0[4] = (short)f2bf(a01.x); pa0[5] = (short)f2bf(a01.y);
    pa0[6] = (short)f2bf(a01.z); pa0[7] = (short)f2bf(a01.w);
    pa1[0] = (short)f2bf(a10.x); pa1[1] = (short)f2bf(a10.y);
    pa1[2] = (short)f2bf(a10.z); pa1[3] = (short)f2bf(a10.w);
    pa1[4] = (short)f2bf(a11.x); pa1[5] = (short)f2bf(a11.y);
    pa1[6] = (short)f2bf(a11.z); pa1[7] = (short)f2bf(a11.w);
    __syncthreads();
    *(bf8_t*)(Al + (size_t)tid * 8) = pa0;
    *(bf8_t*)(Al + (size_t)(256 + tid) * 8) = pa1;
    *(bf8_t*)(Bl + (size_t)tid * 8) = b0;
    *(bf8_t*)(Bl + (size_t)(256 + tid) * 8) = b1;
    __syncthreads();
    bf8_t af[4], bfr[4];
#pragma unroll
    for (int i = 0; i < 4; ++i) {
      af[i]  = *(const bf8_t*)(Al + (qr + i * 16 + (lane & 15)) * 32 + (lane >> 4) * 8);
      bfr[i] = *(const bf8_t*)(Bl + (qc + i * 16 + (lane & 15)) * 32 + (lane >> 4) * 8);
    }
#pragma unroll
    for (int i = 0; i < 4; ++i)
#pragma unroll
      for (int j = 0; j < 4; ++j)
        acc[i][j] = __builtin_amdgcn_mfma_f32_16x16x32_bf16(af[i], bfr[j], acc[i][j], 0, 0, 0);
  }
#pragma unroll
  for (int i = 0; i < 4; ++i)
#pragma unroll
    for (int j = 0; j < 4; ++j)
#pragma unroll
      for (int r = 0; r < 4; ++r) {
        int row = m0 + qr + i * 16 + (lane >> 4) * 4 + r;
        int col = n0 + qc + j * 16 + (lane & 15);
        P[(size_t)row * 1024 + col] = f2bf(acc[i][j][r]);
      }
}

// ---------- K2: pair scan, 2 independent row-groups per block ----------
// 16 pairs x 2 blocks; pair owns 32 batch rows as two 16-row groups A/B.
// Block q owns h cols [q*128,q*128+128) x 4 gates, U-slice in registers.
// One exchange round-trip per step covers both groups (dual-flag poll).
#define OFFX(pp, G, par, qq) ((((((pp) * 2 + (G)) * 2 + (par)) * 2) + (qq)) * 4096)
__global__ __launch_bounds__(512, 2) void k_scan(
    const ushort_t* __restrict__ P, const ushort_t* __restrict__ UPJ,
    const float* __restrict__ bias, const int* __restrict__ cap,
    float* __restrict__ hfin, char* __restrict__ pbuf, unsigned* __restrict__ flags) {
  __shared__ ushort_t hlds[2][2][2048];   // [group][parity]: 4KB each
  const int blk = blockIdx.x;
  const int pair = blk >> 1, q = blk & 1;
  const int tid = threadIdx.x, lane = tid & 63, w = tid >> 6;
  const int l15 = lane & 15, l16 = lane >> 4;
  const int jc = q * 128 + w * 16 + l15;       // this lane's global h col
  const int rowA = pair * 32 + l16 * 4;        // group A batch rows (4 cells)
  const int rowB = rowA + 16;                  // group B batch rows

  // U frags, local-kt order (own half = u[0..3], partner half = u[4..7])
  bf8_t u[8][4];
  {
    const ushort_t* ub = UPJ + (size_t)(q * 8 + w) * 32 * 512 + (size_t)lane * 8;
#pragma unroll
    for (int kt = 0; kt < 8; ++kt)
#pragma unroll
      for (int g = 0; g < 4; ++g)
        u[kt][g] = *(const bf8_t*)(ub + (kt * 4 + g) * 512);
  }
  const float4 bs = *(const float4*)(bias + jc * 4);

  float cA[4] = {0.f, 0.f, 0.f, 0.f}, cB[4] = {0.f, 0.f, 0.f, 0.f};
  f4_t accA[4], accB[4];
#pragma unroll
  for (int g = 0; g < 4; ++g) { accA[g] = f4_t{0.f,0.f,0.f,0.f}; accB[g] = f4_t{0.f,0.f,0.f,0.f}; }

  // prologue: pf for t=0; tok = tokens for t=1
  int tokA[4], tokB[4];
  us4_t pfA[4], pfB[4];
#pragma unroll
  for (int r = 0; r < 4; ++r) { tokA[r] = cap[(rowA + r) * TT]; tokB[r] = cap[(rowB + r) * TT]; }
#pragma unroll
  for (int r = 0; r < 4; ++r) {
    pfA[r] = *(const us4_t*)(P + (size_t)tokA[r] * 1024 + jc * 4);
    pfB[r] = *(const us4_t*)(P + (size_t)tokB[r] * 1024 + jc * 4);
  }
#pragma unroll
  for (int r = 0; r < 4; ++r) { tokA[r] = cap[(rowA + r) * TT + 1]; tokB[r] = cap[(rowB + r) * TT + 1]; }

  const int wfrag = (w >> 1) * 4 + (w & 1) * 2 + (l15 >> 3);
  const int wbase = wfrag * 128 + l16 * 32 + (l15 & 7);
  const int cg = tid >> 8, ct = tid & 255;     // copy role: group + 16B slot

  unsigned* fownA = flags + ((pair * 2 + q) * 2 + 0) * TT;
  unsigned* fownB = flags + ((pair * 2 + q) * 2 + 1) * TT;
  const unsigned* fparA = flags + ((pair * 2 + (1 - q)) * 2 + 0) * TT;
  const unsigned* fparB = flags + ((pair * 2 + (1 - q)) * 2 + 1) * TT;

#define GATES(cX, pfX, accX, hvX)                                        \
  _Pragma("unroll")                                                      \
  for (int r = 0; r < 4; ++r) {                                          \
    float pi = accX[0][r] + bf2f(pfX[r].x) + bs.x;                       \
    float pF = accX[1][r] + bf2f(pfX[r].y) + bs.y;                       \
    float po = accX[2][r] + bf2f(pfX[r].z) + bs.z;                       \
    float pg = accX[3][r] + bf2f(pfX[r].w) + bs.w;                       \
    float ig = sigm(pi), fg = sigm(pF), og = sigm(po), gg = tanh_f(pg);  \
    float cn = fmaf(fg, cX[r], ig * gg);                                 \
    cX[r] = cn;                                                          \
    hvX[r] = og * tanh_f(cn);                                            \
  }

  for (int t = 0; t < TT; ++t) {
    float hvA[4], hvB[4];
    GATES(cA, pfA, accA, hvA)
    GATES(cB, pfB, accB, hvB)
    if (t == TT - 1) {
#pragma unroll
      for (int r = 0; r < 4; ++r) {
        hfin[(size_t)(rowA + r) * 256 + jc] = hvA[r];
        hfin[(size_t)(rowB + r) * 256 + jc] = hvB[r];
      }
      break;
    }
    const int par = t & 1;
    // ---- h -> LDS (A-frag layout), both groups ----
#pragma unroll
    for (int r = 0; r < 4; ++r) {
      hlds[0][par][wbase + r * 8] = f2bf(hvA[r]);
      hlds[1][par][wbase + r * 8] = f2bf(hvB[r]);
    }
    __syncthreads();
    // ---- LDS -> LLC exchange: threads 0-255 copy group A, 256-511 group B ----
    {
      bf8_t v = *(const bf8_t*)(&hlds[cg][par][ct * 8]);
      x_store16(pbuf + OFFX(pair, cg, par, q) + ct * 16, v);
      asm volatile("s_waitcnt vmcnt(0)" ::: "memory");
    }
    __syncthreads();
    if (tid == 0)   x_store_flag(fownA + t, 1u);
    if (tid == 256) x_store_flag(fownB + t, 1u);
    // ---- P/token prefetch for t+1: issued AFTER flags, flies during poll ----
    us4_t pfnA[4], pfnB[4];
    int tokNA[4], tokNB[4];
    {
      const int t2 = (t + 2 < TT) ? t + 2 : TT - 1;
#pragma unroll
      for (int r = 0; r < 4; ++r) {
        pfnA[r] = *(const us4_t*)(P + (size_t)tokA[r] * 1024 + jc * 4);
        pfnB[r] = *(const us4_t*)(P + (size_t)tokB[r] * 1024 + jc * 4);
      }
#pragma unroll
      for (int r = 0; r < 4; ++r) {
        tokNA[r] = cap[(rowA + r) * TT + t2];
        tokNB[r] = cap[(rowB + r) * TT + t2];
      }
    }
    // ---- all lanes: dual-flag poll (one load-pair round trip when set) ----
    {
      unsigned fa, fb;
      for (;;) {
        asm volatile(
            "global_load_dword %0, %2, off sc0 sc1\n\t"
            "global_load_dword %1, %3, off sc0 sc1\n\t"
            "s_waitcnt vmcnt(0)"
            : "=&v"(fa), "=&v"(fb) : "v"(fparA + t), "v"(fparB + t) : "memory");
        if ((fa & fb) != 0u) break;
        __builtin_amdgcn_s_sleep(1);
      }
    }
    // ---- partner frag issue (A then B), own-half MFMAs overlap flight ----
    bf8_t pafA[4], pafB[4];
    x_load4_issue(pbuf + OFFX(pair, 0, par, 1 - q) + (l16 * 16 + l15) * 16, pafA);
    x_load4_issue(pbuf + OFFX(pair, 1, par, 1 - q) + (l16 * 16 + l15) * 16, pafB);
#pragma unroll
    for (int g = 0; g < 4; ++g) { accA[g] = f4_t{0.f,0.f,0.f,0.f}; accB[g] = f4_t{0.f,0.f,0.f,0.f}; }
#pragma unroll
    for (int kt = 0; kt < 4; ++kt) {
      bf8_t afk = *(const bf8_t*)(&hlds[0][par][((kt * 4 + l16) * 16 + l15) * 8]);
#pragma unroll
      for (int g = 0; g < 4; ++g)
        accA[g] = __builtin_amdgcn_mfma_f32_16x16x32_bf16(afk, u[kt][g], accA[g], 0, 0, 0);
    }
#pragma unroll
    for (int kt = 0; kt < 4; ++kt) {
      bf8_t bfk = *(const bf8_t*)(&hlds[1][par][((kt * 4 + l16) * 16 + l15) * 8]);
#pragma unroll
      for (int g = 0; g < 4; ++g)
        accB[g] = __builtin_amdgcn_mfma_f32_16x16x32_bf16(bfk, u[kt][g], accB[g], 0, 0, 0);
    }
    asm volatile("s_waitcnt vmcnt(4)" ::: "memory");   // pafA arrived (in-order count)
    __builtin_amdgcn_sched_barrier(0);
#pragma unroll
    for (int kt = 0; kt < 4; ++kt)
#pragma unroll
      for (int g = 0; g < 4; ++g)
        accA[g] = __builtin_amdgcn_mfma_f32_16x16x32_bf16(pafA[kt], u[4 + kt][g], accA[g], 0, 0, 0);
    asm volatile("s_waitcnt vmcnt(0)" ::: "memory");   // pafB arrived
    __builtin_amdgcn_sched_barrier(0);
#pragma unroll
    for (int kt = 0; kt < 4; ++kt)
#pragma unroll
      for (int g = 0; g < 4; ++g)
        accB[g] = __builtin_amdgcn_mfma_f32_16x16x32_bf16(pafB[kt], u[4 + kt][g], accB[g], 0, 0, 0);
    // roll prefetch state
#pragma unroll
    for (int r = 0; r < 4; ++r) {
      pfA[r] = pfnA[r]; pfB[r] = pfnB[r];
      tokA[r] = tokNA[r]; tokB[r] = tokNB[r];
    }
  }
#undef GATES
}

// ---------- K3: out = normalize(h @ fc_w + fc_b) ----------
__global__ __launch_bounds__(256) void k3_fc(const float* __restrict__ hfin,
                                             const float* __restrict__ fcw,
                                             const float* __restrict__ fcb,
                                             float* __restrict__ out) {
  __shared__ float hrow[256];
  __shared__ float red[4];
  const int b = blockIdx.x, j = threadIdx.x;
  hrow[j] = hfin[(size_t)b * 256 + j];
  __syncthreads();
  float acc = fcb[j];
#pragma unroll 4
  for (int k = 0; k < 256; ++k) acc = fmaf(hrow[k], fcw[(size_t)k * 256 + j], acc);
  float ss = acc * acc;
#pragma unroll
  for (int o = 32; o > 0; o >>= 1) ss += __shfl_down(ss, o);
  if ((j & 63) == 0) red[j >> 6] = ss;
  __syncthreads();
  float tot = red[0] + red[1] + red[2] + red[3];
  float nrm = fmaxf(sqrtf(tot), 1e-12f);
  out[(size_t)b * 256 + j] = acc / nrm;
}

extern "C" void kernel_launch(void* const* d_in, const int* in_sizes, int n_in,
                              void* d_out, int out_size, void* d_ws, size_t ws_size,
                              hipStream_t stream) {
  const int* captions = (const int*)d_in[0];
  const float* emb = (const float*)d_in[1];
  const float *W[4], *bW[4], *U[4], *bU[4];
  for (int g = 0; g < 4; ++g) {
    W[g]  = (const float*)d_in[2 + 4 * g];
    bW[g] = (const float*)d_in[3 + 4 * g];
    U[g]  = (const float*)d_in[4 + 4 * g];
    bU[g] = (const float*)d_in[5 + 4 * g];
  }
  const float* fcw = (const float*)d_in[18];
  const float* fcb = (const float*)d_in[19];
  float* out = (float*)d_out;

  char* ws = (char*)d_ws;
  ushort_t* P     = (ushort_t*)(ws);                 // 32000*1024*2 = 65,536,000
  ushort_t* WT    = (ushort_t*)(ws + 65536000);      // 524,288
  ushort_t* UPJ   = (ushort_t*)(ws + 66060288);      // 524,288
  float*    bias  = (float*)   (ws + 66584576);      // 4,096
  float*    hfin  = (float*)   (ws + 66588672);      // 524,288
  char*     pbuf  = (char*)    (ws + 67112960);      // 16*2*2*2*4096 = 524,288
  unsigned* flags = (unsigned*)(ws + 67637248);      // 16*2*2*128*4  = 32,768

  hipMemsetAsync(flags, 0, 32768, stream);
  k_pack_w<<<1024, 256, 0, stream>>>(W[0], W[1], W[2], W[3], WT);
  k_pack_u<<<128, 256, 0, stream>>>(U[0], U[1], U[2], U[3], UPJ);
  k_bias<<<4, 256, 0, stream>>>(bW[0], bW[1], bW[2], bW[3],
                                bU[0], bU[1], bU[2], bU[3], bias);
  k1_gemm<<<2000, 256, 0, stream>>>(emb, WT, P);
  k_scan<<<32, 512, 0, stream>>>(P, UPJ, bias, captions, hfin, pbuf, flags);
  k3_fc<<<512, 256, 0, stream>>>(hfin, fcw, fcb, out);
}

// Round 7
// 692.668 us; speedup vs baseline: 1.8617x; 1.8617x over previous
//
#include <hip/hip_runtime.h>
#include <stdint.h>

typedef unsigned short ushort_t;
typedef __attribute__((ext_vector_type(8))) short bf8_t;     // 8 x bf16 (4 VGPRs)
typedef __attribute__((ext_vector_type(4))) float f4_t;      // MFMA accumulator
typedef __attribute__((ext_vector_type(4))) unsigned short us4_t;

#define TT 128
#define NREG 46                     // U fragments in registers per wave (of 64)
#define NLDS 18                     // U fragments in LDS per wave
#define HOFF 73728                  // ushort offset of h buffer in dynamic LDS (144KB/2)

__device__ __forceinline__ ushort_t f2bf(float f) {
  uint32_t u = __builtin_bit_cast(uint32_t, f);
  u += 0x7fffu + ((u >> 16) & 1u);
  return (ushort_t)(u >> 16);
}
__device__ __forceinline__ float bf2f(ushort_t h) {
  uint32_t u = ((uint32_t)h) << 16;
  return __builtin_bit_cast(float, u);
}
__device__ __forceinline__ float sigm(float x) {
  return __builtin_amdgcn_rcpf(1.f + __expf(-x));
}
__device__ __forceinline__ float tanh_f(float x) {
  return 1.f - 2.f * __builtin_amdgcn_rcpf(1.f + __expf(2.f * x));
}

// ---------- pack kernels ----------
// Gate-interleaved: physical output col n = col*4 + gate.  WT[n][k] = W_{g=n&3}[k][j=n>>2]
__global__ void k_pack_w(const float* W0, const float* W1, const float* W2, const float* W3,
                         ushort_t* __restrict__ o) {
  int idx = blockIdx.x * 256 + threadIdx.x;   // 0..262143
  int n = idx >> 8, k = idx & 255;
  int g = n & 3, j = n >> 2;
  const float* Wg = g == 0 ? W0 : g == 1 ? W1 : g == 2 ? W2 : W3;
  o[(size_t)n * 256 + k] = f2bf(Wg[k * 256 + j]);
}

// U frag pack, pass-major order: frag fi = ct2*32 + kt*4 + g for wave w.
// elem offset = ((w*64 + fi)*64 + lane)*8 + e.
// col = w*32 + ct2*16 + (lane&15); k = kt*32 + (lane>>4)*8 + e; val = U_g[k][col]
__global__ void k_pack_u(const float* U0, const float* U1, const float* U2, const float* U3,
                         ushort_t* __restrict__ o) {
  int idx = blockIdx.x * 256 + threadIdx.x;   // 0..32767
  int lane = idx & 63, g = (idx >> 6) & 3, kt = (idx >> 8) & 7,
      ct2 = (idx >> 11) & 1, w = (idx >> 12) & 7;
  const float* Ug = g == 0 ? U0 : g == 1 ? U1 : g == 2 ? U2 : U3;
  int col = w * 32 + ct2 * 16 + (lane & 15);
  int kb = kt * 32 + (lane >> 4) * 8;
#pragma unroll
  for (int e = 0; e < 8; ++e)
    o[(size_t)idx * 8 + e] = f2bf(Ug[(size_t)(kb + e) * 256 + col]);
}

// bias2[n] (n = j*4+g) = bW_g[j] + bU_g[j]   (folded into P by k1)
__global__ void k_bias(const float* a0, const float* a1, const float* a2, const float* a3,
                       const float* b0, const float* b1, const float* b2, const float* b3,
                       float* __restrict__ o) {
  int n = blockIdx.x * 256 + threadIdx.x;  // 0..1023
  int g = n & 3, j = n >> 2;
  const float* pa = g == 0 ? a0 : g == 1 ? a1 : g == 2 ? a2 : a3;
  const float* pb = g == 0 ? b0 : g == 1 ? b1 : g == 2 ? b2 : b3;
  o[n] = pa[j] + pb[j];
}

// ---------- K1: P = emb @ W_all + bias (bias folded; bf16 MFMA) ----------
__global__ __launch_bounds__(256) void k1_gemm(const float* __restrict__ A,      // emb f32 [32000][256]
                                               const ushort_t* __restrict__ Bm,  // WT bf16 [1024][256]
                                               const float* __restrict__ bias,   // [1024]
                                               ushort_t* __restrict__ P) {       // [32000][1024]
  __shared__ ushort_t Al[128 * 32];
  __shared__ ushort_t Bl[128 * 32];
  const int tid = threadIdx.x;
  const int lane = tid & 63;
  const int w = tid >> 6;
  const int mt = blockIdx.x >> 3;
  const int nt = blockIdx.x & 7;
  const int m0 = mt * 128, n0 = nt * 128;
  const int qr = (w >> 1) * 64, qc = (w & 1) * 64;

  f4_t acc[4][4];
#pragma unroll
  for (int i = 0; i < 4; ++i)
#pragma unroll
    for (int j = 0; j < 4; ++j) acc[i][j] = f4_t{0.f, 0.f, 0.f, 0.f};

  const int r0 = tid >> 2, s0 = tid & 3;  // rows 0..63
  const int r1 = 64 + r0;                 // rows 64..127

  for (int k0 = 0; k0 < 256; k0 += 32) {
    float4 a00 = *(const float4*)(A + (size_t)(m0 + r0) * 256 + k0 + s0 * 8);
    float4 a01 = *(const float4*)(A + (size_t)(m0 + r0) * 256 + k0 + s0 * 8 + 4);
    float4 a10 = *(const float4*)(A + (size_t)(m0 + r1) * 256 + k0 + s0 * 8);
    float4 a11 = *(const float4*)(A + (size_t)(m0 + r1) * 256 + k0 + s0 * 8 + 4);
    bf8_t b0 = *(const bf8_t*)(Bm + (size_t)(n0 + r0) * 256 + k0 + s0 * 8);
    bf8_t b1 = *(const bf8_t*)(Bm + (size_t)(n0 + r1) * 256 + k0 + s0 * 8);
    bf8_t pa0, pa1;
    pa0[0] = (short)f2bf(a00.x); pa0[1] = (short)f2bf(a00.y);
    pa0[2] = (short)f2bf(a00.z); pa0[3] = (short)f2bf(a00.w);
    pa0[4] = (short)f2bf(a01.x); pa0[5] = (short)f2bf(a01.y);
    pa0[6] = (short)f2bf(a01.z); pa0[7] = (short)f2bf(a01.w);
    pa1[0] = (short)f2bf(a10.x); pa1[1] = (short)f2bf(a10.y);
    pa1[2] = (short)f2bf(a10.z); pa1[3] = (short)f2bf(a10.w);
    pa1[4] = (short)f2bf(a11.x); pa1[5] = (short)f2bf(a11.y);
    pa1[6] = (short)f2bf(a11.z); pa1[7] = (short)f2bf(a11.w);
    __syncthreads();
    *(bf8_t*)(Al + (size_t)tid * 8) = pa0;
    *(bf8_t*)(Al + (size_t)(256 + tid) * 8) = pa1;
    *(bf8_t*)(Bl + (size_t)tid * 8) = b0;
    *(bf8_t*)(Bl + (size_t)(256 + tid) * 8) = b1;
    __syncthreads();
    bf8_t af[4], bfr[4];
#pragma unroll
    for (int i = 0; i < 4; ++i) {
      af[i]  = *(const bf8_t*)(Al + (qr + i * 16 + (lane & 15)) * 32 + (lane >> 4) * 8);
      bfr[i] = *(const bf8_t*)(Bl + (qc + i * 16 + (lane & 15)) * 32 + (lane >> 4) * 8);
    }
#pragma unroll
    for (int i = 0; i < 4; ++i)
#pragma unroll
      for (int j = 0; j < 4; ++j)
        acc[i][j] = __builtin_amdgcn_mfma_f32_16x16x32_bf16(af[i], bfr[j], acc[i][j], 0, 0, 0);
  }
#pragma unroll
  for (int i = 0; i < 4; ++i)
#pragma unroll
    for (int j = 0; j < 4; ++j)
#pragma unroll
      for (int r = 0; r < 4; ++r) {
        int row = m0 + qr + i * 16 + (lane >> 4) * 4 + r;
        int col = n0 + qc + j * 16 + (lane & 15);
        P[(size_t)row * 1024 + col] = f2bf(acc[i][j][r] + bias[col]);
      }
}

// U fragment access: regs for fi < NREG, LDS otherwise (fi always compile-time const)
#define UF(fi) ((fi) < NREG ? u[(fi) < NREG ? (fi) : 0]                                  \
                            : *(const bf8_t*)(&sh[(w * NLDS + ((fi) < NREG ? 0 : (fi) - NREG)) * 512 + lane * 8]))

// ---------- K2: single-CU scan — U fully resident (regs + LDS), no cross-block sync ----------
// 32 blocks x 16 batch rows, 512 threads (8 waves @ <=256 VGPR). Wave w owns hidden
// cols [w*32, w*32+32) x 4 gates: 64 B-frags = 46 in VGPRs + 18 in LDS (144KB).
// h(t) (16x256 bf16, 8KB) lives in LDS in A-frag layout; 2 barriers/step.
__global__ __launch_bounds__(512, 2) void k_scan(
    const ushort_t* __restrict__ P, const ushort_t* __restrict__ UPJ,
    const int* __restrict__ cap, float* __restrict__ hfin) {
  extern __shared__ ushort_t sh[];
  const int b = blockIdx.x;
  const int tid = threadIdx.x, lane = tid & 63, w = tid >> 6;
  const int l15 = lane & 15, l16 = lane >> 4;
  const int row0 = b * 16 + l16 * 4;           // this lane's 4 batch rows

  // preload U: 46 frags -> registers, 18 frags -> LDS
  bf8_t u[NREG];
#pragma unroll
  for (int fi = 0; fi < NREG; ++fi)
    u[fi] = *(const bf8_t*)(UPJ + ((size_t)w * 64 + fi) * 512 + (size_t)lane * 8);
#pragma unroll
  for (int s = 0; s < NLDS; ++s) {
    bf8_t v = *(const bf8_t*)(UPJ + ((size_t)w * 64 + NREG + s) * 512 + (size_t)lane * 8);
    *(bf8_t*)(&sh[(w * NLDS + s) * 512 + lane * 8]) = v;
  }
  __syncthreads();

  int tok[4];
#pragma unroll
  for (int r = 0; r < 4; ++r) tok[r] = cap[(row0 + r) * TT];

  float c[2][4], hv[2][4];
#pragma unroll
  for (int i = 0; i < 2; ++i)
#pragma unroll
    for (int r = 0; r < 4; ++r) c[i][r] = 0.f;

  for (int t = 0; t < TT; ++t) {
    if (t > 0) __syncthreads();                // h(t-1) writes visible
#pragma unroll
    for (int ct2 = 0; ct2 < 2; ++ct2) {
      const int jcol = w * 32 + ct2 * 16 + l15;
      // P quads (bias pre-folded): issued first, latency hides under MFMAs
      us4_t pf[4];
#pragma unroll
      for (int r = 0; r < 4; ++r)
        pf[r] = *(const us4_t*)(P + (size_t)tok[r] * 1024 + jcol * 4);

      f4_t a0 = {0.f,0.f,0.f,0.f}, a1 = a0, a2 = a0, a3 = a0;
      if (t > 0) {
#pragma unroll
        for (int kt = 0; kt < 8; ++kt) {
          bf8_t af = *(const bf8_t*)(&sh[HOFF + (((kt * 4 + l16) * 16) + l15) * 8]);
          a0 = __builtin_amdgcn_mfma_f32_16x16x32_bf16(af, UF(ct2 * 32 + kt * 4 + 0), a0, 0, 0, 0);
          a1 = __builtin_amdgcn_mfma_f32_16x16x32_bf16(af, UF(ct2 * 32 + kt * 4 + 1), a1, 0, 0, 0);
          a2 = __builtin_amdgcn_mfma_f32_16x16x32_bf16(af, UF(ct2 * 32 + kt * 4 + 2), a2, 0, 0, 0);
          a3 = __builtin_amdgcn_mfma_f32_16x16x32_bf16(af, UF(ct2 * 32 + kt * 4 + 3), a3, 0, 0, 0);
        }
      }
      // gates + cell update (4 cells: rows row0..row0+3, col jcol)
#pragma unroll
      for (int r = 0; r < 4; ++r) {
        float pi = a0[r] + bf2f(pf[r].x);
        float pF = a1[r] + bf2f(pf[r].y);
        float po = a2[r] + bf2f(pf[r].z);
        float pg = a3[r] + bf2f(pf[r].w);
        float cn = fmaf(sigm(pF), c[ct2][r], sigm(pi) * tanh_f(pg));
        c[ct2][r] = cn;
        hv[ct2][r] = sigm(po) * tanh_f(cn);
      }
    }
    // tokens for t+1 (cheap L2 hits, a full step to arrive)
    {
      const int t1 = (t + 1 < TT) ? t + 1 : TT - 1;
#pragma unroll
      for (int r = 0; r < 4; ++r) tok[r] = cap[(row0 + r) * TT + t1];
    }
    if (t == TT - 1) {
#pragma unroll
      for (int ct2 = 0; ct2 < 2; ++ct2)
#pragma unroll
        for (int r = 0; r < 4; ++r)
          hfin[(size_t)(row0 + r) * 256 + w * 32 + ct2 * 16 + l15] = hv[ct2][r];
    } else {
      __syncthreads();                         // all reads of h(t-1) complete
      // write h(t) in A-frag layout: jcol -> (kt=w, sub, e), row -> slot
#pragma unroll
      for (int ct2 = 0; ct2 < 2; ++ct2) {
        const int sub = ct2 * 2 + (l15 >> 3), e = l15 & 7;
#pragma unroll
        for (int r = 0; r < 4; ++r)
          sh[HOFF + (((w * 4 + sub) * 16) + l16 * 4 + r) * 8 + e] = f2bf(hv[ct2][r]);
      }
    }
  }
}

// ---------- K3: out = normalize(h @ fc_w + fc_b) ----------
__global__ __launch_bounds__(256) void k3_fc(const float* __restrict__ hfin,
                                             const float* __restrict__ fcw,
                                             const float* __restrict__ fcb,
                                             float* __restrict__ out) {
  __shared__ float hrow[256];
  __shared__ float red[4];
  const int b = blockIdx.x, j = threadIdx.x;
  hrow[j] = hfin[(size_t)b * 256 + j];
  __syncthreads();
  float acc = fcb[j];
#pragma unroll 4
  for (int k = 0; k < 256; ++k) acc = fmaf(hrow[k], fcw[(size_t)k * 256 + j], acc);
  float ss = acc * acc;
#pragma unroll
  for (int o = 32; o > 0; o >>= 1) ss += __shfl_down(ss, o);
  if ((j & 63) == 0) red[j >> 6] = ss;
  __syncthreads();
  float tot = red[0] + red[1] + red[2] + red[3];
  float nrm = fmaxf(sqrtf(tot), 1e-12f);
  out[(size_t)b * 256 + j] = acc / nrm;
}

extern "C" void kernel_launch(void* const* d_in, const int* in_sizes, int n_in,
                              void* d_out, int out_size, void* d_ws, size_t ws_size,
                              hipStream_t stream) {
  const int* captions = (const int*)d_in[0];
  const float* emb = (const float*)d_in[1];
  const float *W[4], *bW[4], *U[4], *bU[4];
  for (int g = 0; g < 4; ++g) {
    W[g]  = (const float*)d_in[2 + 4 * g];
    bW[g] = (const float*)d_in[3 + 4 * g];
    U[g]  = (const float*)d_in[4 + 4 * g];
    bU[g] = (const float*)d_in[5 + 4 * g];
  }
  const float* fcw = (const float*)d_in[18];
  const float* fcb = (const float*)d_in[19];
  float* out = (float*)d_out;

  char* ws = (char*)d_ws;
  ushort_t* P    = (ushort_t*)(ws);                 // 32000*1024*2 = 65,536,000
  ushort_t* WT   = (ushort_t*)(ws + 65536000);      // 524,288
  ushort_t* UPJ  = (ushort_t*)(ws + 66060288);      // 524,288
  float*    bias = (float*)   (ws + 66584576);      // 4,096
  float*    hfin = (float*)   (ws + 66588672);      // 524,288

  // dynamic LDS for k_scan: 144KB U-frags + 8KB h = 152KB
  const int scan_lds = (NLDS * 8 * 1024) + 8192;    // 155,648 bytes
  hipFuncSetAttribute((const void*)k_scan,
                      hipFuncAttributeMaxDynamicSharedMemorySize, scan_lds);

  k_pack_w<<<1024, 256, 0, stream>>>(W[0], W[1], W[2], W[3], WT);
  k_pack_u<<<128, 256, 0, stream>>>(U[0], U[1], U[2], U[3], UPJ);
  k_bias<<<4, 256, 0, stream>>>(bW[0], bW[1], bW[2], bW[3],
                                bU[0], bU[1], bU[2], bU[3], bias);
  k1_gemm<<<2000, 256, 0, stream>>>(emb, WT, bias, P);
  k_scan<<<32, 512, scan_lds, stream>>>(P, UPJ, captions, hfin);
  k3_fc<<<512, 256, 0, stream>>>(hfin, fcw, fcb, out);
}